// Round 7
// baseline (437.832 us; speedup 1.0000x reference)
//
#include <hip/hip_runtime.h>

// AttentionWindow: out = repr + relu(softmax_masked((repr@W)@repr^T) @ repr)
// BATCH=8, SEQ=2048, HIDDEN=1024, window half-width 64 (|i-j|>64 masked).
//
// Modes (uniform data sniff):
//   bf16 data  -> attn_mfma      (verified; unchanged, 256 thr)
//   fp32 data  -> attn_mfma_f32  (R7: 512 threads / 8 waves -> 4 waves/SIMD,
//                                 work-per-wave halved; __syncthreads
//                                 restored. R5 base: fragment-order Wf
//                                 global->reg B-operands, RQ dbuf, VT swizzle)
//   no workspace -> proven VALU pair.

#define SEQL 2048
#define HID  1024
#define NB   8
#define QT   32
#define KT   160
#define DCO  128
#define EC   32
#define DS   32
#define RP   36
#define WP   132
#define QP   132
#define KP   36
#define SP   161

#define RS_OFF  0
#define WS_OFF  1152
#define KS_OFF  0
#define QCS_OFF 5760
#define SC_OFF  5760
#define SMEM_F  10912

__device__ __forceinline__ float bfu(unsigned int lo16) {
  union { unsigned int i; float f; } v; v.i = lo16 << 16; return v.f;
}
__device__ __forceinline__ unsigned short f2bf(float f) {
  union { float f; unsigned int i; } v; v.f = f;
  unsigned int r = v.i + 0x7FFFu + ((v.i >> 16) & 1u);   // RNE
  return (unsigned short)(r >> 16);
}
__device__ __forceinline__ void hilo(float v, unsigned short& h, unsigned short& l) {
  h = f2bf(v);
  l = f2bf(v - bfu(h));
}

// Uniform dtype sniff (thread-invariant).
__device__ bool data_is_bf16(const unsigned short* u) {
  int cnt = 0;
  for (int i = 0; i < 256; i++) {
    int e = (u[i] >> 7) & 0xFF;
    if (e >= 107 && e <= 131) cnt++;
  }
  return cnt >= 230;
}

template<bool BF16>
__device__ __forceinline__ float4 ld4(const void* p, size_t idx) {
  if (BF16) {
    uint2 u = *(const uint2*)((const unsigned short*)p + idx);
    float4 r;
    r.x = bfu(u.x & 0xFFFFu); r.y = bfu(u.x >> 16);
    r.z = bfu(u.y & 0xFFFFu); r.w = bfu(u.y >> 16);
    return r;
  } else {
    return *(const float4*)((const float*)p + idx);
  }
}

template<bool BF16>
__device__ __forceinline__ void st4(void* p, size_t idx, float4 v) {
  if (BF16) {
    ushort4 o;
    o.x = f2bf(v.x); o.y = f2bf(v.y); o.z = f2bf(v.z); o.w = f2bf(v.w);
    *(ushort4*)((unsigned short*)p + idx) = o;
  } else {
    *(float4*)((float*)p + idx) = v;
  }
}

__device__ __forceinline__ void fma4(float4& q, float a, const float4& w) {
  q.x += a * w.x; q.y += a * w.y; q.z += a * w.z; q.w += a * w.w;
}

// ---------------------------------------------------------------------------
// OLD proven VALU kernel (fallback when no workspace)
// ---------------------------------------------------------------------------
template<bool BF16>
__global__ void __launch_bounds__(256) attn_fused(
    const void* __restrict__ reprv, const void* __restrict__ Wv,
    void* __restrict__ outv) {
  if (data_is_bf16((const unsigned short*)reprv) != BF16) return;

  __shared__ float smem[SMEM_F];
  const int tid = threadIdx.x;
  const int b = blockIdx.y;
  const int q0 = blockIdx.x * QT;
  const size_t baseR = (size_t)b * SEQL * HID;

  const int tx = tid & 31, ty = tid >> 5;

  float acc[4][5];
#pragma unroll
  for (int i = 0; i < 4; i++)
#pragma unroll
    for (int j = 0; j < 5; j++) acc[i][j] = 0.f;

  for (int d0 = 0; d0 < HID; d0 += DCO) {
    float4 qc[4];
#pragma unroll
    for (int i = 0; i < 4; i++) qc[i] = make_float4(0.f, 0.f, 0.f, 0.f);

    for (int e0 = 0; e0 < HID; e0 += EC) {
      {
        int row = tid >> 3, cg = tid & 7;
        float4 v = ld4<BF16>(reprv, baseR + (size_t)(q0 + row) * HID + e0 + 4 * cg);
        *(float4*)&smem[RS_OFF + row * RP + 4 * cg] = v;
      }
#pragma unroll
      for (int i2 = 0; i2 < 4; i2++) {
        int f = i2 * 256 + tid;
        int row = f >> 5, cg = f & 31;
        float4 v = ld4<BF16>(Wv, (size_t)(e0 + row) * HID + d0 + 4 * cg);
        *(float4*)&smem[WS_OFF + row * WP + 4 * cg] = v;
      }
      __syncthreads();
#pragma unroll
      for (int ee = 0; ee < EC; ee += 4) {
        float4 rv[4];
#pragma unroll
        for (int i = 0; i < 4; i++)
          rv[i] = *(const float4*)&smem[RS_OFF + (ty + 8 * i) * RP + ee];
        {
          float4 wv = *(const float4*)&smem[WS_OFF + (ee + 0) * WP + 4 * tx];
          fma4(qc[0], rv[0].x, wv); fma4(qc[1], rv[1].x, wv);
          fma4(qc[2], rv[2].x, wv); fma4(qc[3], rv[3].x, wv);
        }
        {
          float4 wv = *(const float4*)&smem[WS_OFF + (ee + 1) * WP + 4 * tx];
          fma4(qc[0], rv[0].y, wv); fma4(qc[1], rv[1].y, wv);
          fma4(qc[2], rv[2].y, wv); fma4(qc[3], rv[3].y, wv);
        }
        {
          float4 wv = *(const float4*)&smem[WS_OFF + (ee + 2) * WP + 4 * tx];
          fma4(qc[0], rv[0].z, wv); fma4(qc[1], rv[1].z, wv);
          fma4(qc[2], rv[2].z, wv); fma4(qc[3], rv[3].z, wv);
        }
        {
          float4 wv = *(const float4*)&smem[WS_OFF + (ee + 3) * WP + 4 * tx];
          fma4(qc[0], rv[0].w, wv); fma4(qc[1], rv[1].w, wv);
          fma4(qc[2], rv[2].w, wv); fma4(qc[3], rv[3].w, wv);
        }
      }
      __syncthreads();
    }

#pragma unroll
    for (int i = 0; i < 4; i++)
      *(float4*)&smem[QCS_OFF + (ty + 8 * i) * QP + 4 * tx] = qc[i];

    for (int s = 0; s < DCO; s += DS) {
#pragma unroll
      for (int i2 = 0; i2 < 5; i2++) {
        int f = i2 * 256 + tid;
        int row = f >> 3, cg = f & 7;
        int kk = q0 - 64 + row;
        kk = kk < 0 ? 0 : (kk > SEQL - 1 ? SEQL - 1 : kk);
        float4 v = ld4<BF16>(reprv, baseR + (size_t)kk * HID + d0 + s + 4 * cg);
        *(float4*)&smem[KS_OFF + row * KP + 4 * cg] = v;
      }
      __syncthreads();
#pragma unroll
      for (int dd = 0; dd < DS; dd += 4) {
        float4 qv[4];
#pragma unroll
        for (int i = 0; i < 4; i++)
          qv[i] = *(const float4*)&smem[QCS_OFF + (ty + 8 * i) * QP + s + dd];
#pragma unroll
        for (int j = 0; j < 5; j++) {
          float4 kv = *(const float4*)&smem[KS_OFF + (tx + 32 * j) * KP + dd];
#pragma unroll
          for (int i = 0; i < 4; i++)
            acc[i][j] += qv[i].x * kv.x + qv[i].y * kv.y + qv[i].z * kv.z + qv[i].w * kv.w;
        }
      }
      __syncthreads();
    }
  }

#pragma unroll
  for (int i = 0; i < 4; i++)
#pragma unroll
    for (int j = 0; j < 5; j++)
      smem[SC_OFF + (ty + 8 * i) * SP + tx + 32 * j] = acc[i][j];
  __syncthreads();

  {
    const int row = tid >> 3, l8 = tid & 7;
    int clo = row;          { int t = 64 - q0;            if (t > clo) clo = t; }
    int chi = row + 128;    { int t = SEQL - 1 + 64 - q0; if (t < chi) chi = t; }
    float m = -1e30f;
    for (int c = l8; c < KT; c += 8)
      if (c >= clo && c <= chi) m = fmaxf(m, smem[SC_OFF + row * SP + c]);
    m = fmaxf(m, __shfl_xor(m, 1));
    m = fmaxf(m, __shfl_xor(m, 2));
    m = fmaxf(m, __shfl_xor(m, 4));
    float ssum = 0.f;
    for (int c = l8; c < KT; c += 8) {
      float e = (c >= clo && c <= chi) ? __expf(smem[SC_OFF + row * SP + c] - m) : 0.f;
      smem[SC_OFF + row * SP + c] = e;
      ssum += e;
    }
    ssum += __shfl_xor(ssum, 1);
    ssum += __shfl_xor(ssum, 2);
    ssum += __shfl_xor(ssum, 4);
    float rinv = 1.f / ssum;
    for (int c = l8; c < KT; c += 8) smem[SC_OFF + row * SP + c] *= rinv;
  }
  __syncthreads();

  const int rr = tid >> 3, dq = tid & 7;
  for (int d0 = 0; d0 < HID; d0 += DS) {
#pragma unroll
    for (int i2 = 0; i2 < 5; i2++) {
      int f = i2 * 256 + tid;
      int row = f >> 3, cg = f & 7;
      int kk = q0 - 64 + row;
      kk = kk < 0 ? 0 : (kk > SEQL - 1 ? SEQL - 1 : kk);
      float4 v = ld4<BF16>(reprv, baseR + (size_t)kk * HID + d0 + 4 * cg);
      *(float4*)&smem[KS_OFF + row * KP + 4 * cg] = v;
    }
    __syncthreads();
    float4 o = make_float4(0.f, 0.f, 0.f, 0.f);
#pragma unroll 4
    for (int c = 0; c < KT; c++) {
      float4 kv = *(const float4*)&smem[KS_OFF + c * KP + 4 * dq];
      float p = smem[SC_OFF + rr * SP + c];
      o.x += p * kv.x; o.y += p * kv.y; o.z += p * kv.z; o.w += p * kv.w;
    }
    size_t goff = baseR + (size_t)(q0 + rr) * HID + d0 + 4 * dq;
    float4 rv = ld4<BF16>(reprv, goff);
    float4 ov;
    ov.x = rv.x + fmaxf(o.x, 0.f);
    ov.y = rv.y + fmaxf(o.y, 0.f);
    ov.z = rv.z + fmaxf(o.z, 0.f);
    ov.w = rv.w + fmaxf(o.w, 0.f);
    st4<BF16>(outv, goff, ov);
    __syncthreads();
  }
}

// ---------------------------------------------------------------------------
// MFMA common
// ---------------------------------------------------------------------------
typedef float f32x4 __attribute__((ext_vector_type(4)));
typedef short bf16x8 __attribute__((ext_vector_type(8)));

#define MF(a_, b_, c_) __builtin_amdgcn_mfma_f32_16x16x32_bf16((a_), (b_), (c_), 0, 0, 0)

// W-transpose (dual-mode).
//  bf16 data: Wt bf16 linear [e][d] @ws0 (2MB, exact) — for attn_mfma.
//  fp32 data: FRAGMENT-ordered hi/lo split for direct global->register
//    B-operand loads in attn_mfma_f32:
//    dest_ush(e,d) = (((e>>4)<<5)|(d>>5))*512 + ((((d>>3)&3)<<4)|(e&15))*8 + (d&7)
//    WfH @ws0 (2MB), WfL @ws+2MB.
__global__ void __launch_bounds__(256) tposeW2(
    const void* __restrict__ reprv, const void* __restrict__ Wv,
    void* __restrict__ wsv) {
  const bool isbf = data_is_bf16((const unsigned short*)reprv);
  __shared__ alignas(16) unsigned char twsb[64 * 68 * 4];
  const int t = threadIdx.x;
  const int d0 = (blockIdx.x & 15) * 64, e0 = (blockIdx.x >> 4) * 64;
  if (isbf) {
    unsigned short* tl = (unsigned short*)twsb;
    const unsigned short* WB = (const unsigned short*)Wv;
    unsigned short* WtB = (unsigned short*)wsv;
#pragma unroll
    for (int i = 0; i < 2; i++) {
      int slot = i * 256 + t, row = slot >> 3, c8 = slot & 7;
      *(uint4*)(tl + row * 72 + 8 * c8) =
          *(const uint4*)(WB + (size_t)(d0 + row) * 1024 + e0 + 8 * c8);
    }
    __syncthreads();
#pragma unroll
    for (int i = 0; i < 2; i++) {
      int slot = i * 256 + t, er = slot >> 3, c8 = slot & 7;
      unsigned short v[8];
#pragma unroll
      for (int j = 0; j < 8; j++) v[j] = tl[(8 * c8 + j) * 72 + er];
      *(uint4*)(WtB + (size_t)(e0 + er) * 1024 + d0 + 8 * c8) = *(const uint4*)v;
    }
  } else {
    float* tlf = (float*)twsb;
    const float* WF = (const float*)Wv;
    unsigned short* WfH = (unsigned short*)wsv;
    unsigned short* WfL = WfH + (1u << 20);   // +2 MB
#pragma unroll
    for (int i = 0; i < 4; i++) {
      int slot = i * 256 + t, row = slot >> 4, cf = slot & 15;
      *(float4*)&tlf[row * 68 + 4 * cf] =
          *(const float4*)(WF + (size_t)(d0 + row) * 1024 + e0 + 4 * cf);
    }
    __syncthreads();
#pragma unroll
    for (int i = 0; i < 2; i++) {
      int slot = i * 256 + t, er = slot >> 3, c8 = slot & 7;
      int e = e0 + er;
      int dg = d0 + 8 * c8;
      unsigned short vh[8], vl[8];
#pragma unroll
      for (int j = 0; j < 8; j++) {
        float v = tlf[(8 * c8 + j) * 68 + er];
        hilo(v, vh[j], vl[j]);
      }
      size_t dst = (size_t)(((e >> 4) << 5) | (dg >> 5)) * 512
                 + (size_t)(((((dg >> 3) & 3) << 4) | (e & 15))) * 8;
      *(uint4*)(WfH + dst) = *(const uint4*)vh;
      *(uint4*)(WfL + dst) = *(const uint4*)vl;
    }
  }
}

// ---------------------------------------------------------------------------
// bf16-data MFMA kernel (round-1 verified, unchanged, 256 threads)
// ---------------------------------------------------------------------------
#define WTS_O 0
#define RQS_O 9216
#define RK_O  11520
#define QHI_O 17920
#define QLO_O 22272
#define PBF_O 11008
#define VT_O  16384
#define SMEMU 27136

__global__ void __launch_bounds__(256, 2) attn_mfma(
    const unsigned short* __restrict__ reprB,
    const unsigned short* __restrict__ WtB,
    unsigned short* __restrict__ outB) {
  if (!data_is_bf16(reprB)) return;

  __shared__ alignas(16) unsigned short sm[SMEMU];
  float* smf = (float*)sm;

  const int tid = threadIdx.x;
  const int w = tid >> 6, l = tid & 63, lr = l & 15, lg = l >> 4;
  const int b = blockIdx.y, q0 = blockIdx.x * 32;
  const size_t baseR = (size_t)b * 2048 * 1024;
  const int qt = w >> 1;
  const int ktb = (w & 1) * 5;

  f32x4 acc_s[5];
#pragma unroll
  for (int j = 0; j < 5; j++) acc_s[j] = (f32x4){0.f, 0.f, 0.f, 0.f};

  for (int ec = 0; ec < 8; ec++) {
    const int e0 = ec * 128;
    f32x4 acc_q[2][2];
#pragma unroll
    for (int i = 0; i < 2; i++)
#pragma unroll
      for (int j = 0; j < 2; j++) acc_q[i][j] = (f32x4){0.f, 0.f, 0.f, 0.f};

    for (int s = 0; s < 16; s++) {
      const int d0 = s * 64;
      uint4 wtr[4], rqr;
#pragma unroll
      for (int i = 0; i < 4; i++) {
        int slot = i * 256 + tid, row = slot >> 3, c8 = slot & 7;
        wtr[i] = *(const uint4*)(WtB + (size_t)(e0 + row) * 1024 + d0 + 8 * c8);
      }
      {
        int row = tid >> 3, c8 = tid & 7;
        rqr = *(const uint4*)(reprB + baseR + (size_t)(q0 + row) * 1024 + d0 + 8 * c8);
      }
      __syncthreads();
#pragma unroll
      for (int i = 0; i < 4; i++) {
        int slot = i * 256 + tid, row = slot >> 3, c8 = slot & 7;
        *(uint4*)(sm + WTS_O + row * 72 + 8 * c8) = wtr[i];
      }
      {
        int row = tid >> 3, c8 = tid & 7;
        *(uint4*)(sm + RQS_O + row * 72 + 8 * c8) = rqr;
      }
      __syncthreads();
#pragma unroll
      for (int h = 0; h < 2; h++) {
        bf16x8 a0 = *(const bf16x8*)(sm + RQS_O + (lr) * 72 + 32 * h + 8 * lg);
        bf16x8 a1 = *(const bf16x8*)(sm + RQS_O + (16 + lr) * 72 + 32 * h + 8 * lg);
        bf16x8 b0 = *(const bf16x8*)(sm + WTS_O + (32 * w + lr) * 72 + 32 * h + 8 * lg);
        bf16x8 b1 = *(const bf16x8*)(sm + WTS_O + (32 * w + 16 + lr) * 72 + 32 * h + 8 * lg);
        acc_q[0][0] = MF(a0, b0, acc_q[0][0]);
        acc_q[0][1] = MF(a0, b1, acc_q[0][1]);
        acc_q[1][0] = MF(a1, b0, acc_q[1][0]);
        acc_q[1][1] = MF(a1, b1, acc_q[1][1]);
      }
    }

#pragma unroll
    for (int qq = 0; qq < 2; qq++)
#pragma unroll
      for (int et = 0; et < 2; et++)
#pragma unroll
        for (int r = 0; r < 4; r++) {
          int row = 16 * qq + 4 * lg + r;
          int col = 32 * w + 16 * et + lr;
          float v = acc_q[qq][et][r];
          unsigned short hi = f2bf(v);
          sm[QHI_O + row * 136 + col] = hi;
          sm[QLO_O + row * 136 + col] = f2bf(v - bfu(hi));
        }

    for (int es = 0; es < 4; es++) {
      uint4 rkr[3];
#pragma unroll
      for (int i = 0; i < 3; i++) {
        int slot = i * 256 + tid;
        if (slot < 640) {
          int row = slot >> 2, c8 = slot & 3;
          int kk = q0 - 64 + row;
          kk = kk < 0 ? 0 : (kk > 2047 ? 2047 : kk);
          rkr[i] = *(const uint4*)(reprB + baseR + (size_t)kk * 1024 + e0 + 32 * es + 8 * c8);
        }
      }
      __syncthreads();
#pragma unroll
      for (int i = 0; i < 3; i++) {
        int slot = i * 256 + tid;
        if (slot < 640) {
          int row = slot >> 2, c8 = slot & 3;
          *(uint4*)(sm + RK_O + row * 40 + 8 * c8) = rkr[i];
        }
      }
      __syncthreads();
      bf16x8 qh = *(const bf16x8*)(sm + QHI_O + (16 * qt + lr) * 136 + 32 * es + 8 * lg);
      bf16x8 ql = *(const bf16x8*)(sm + QLO_O + (16 * qt + lr) * 136 + 32 * es + 8 * lg);
#pragma unroll
      for (int j = 0; j < 5; j++) {
        bf16x8 kv = *(const bf16x8*)(sm + RK_O + (16 * (ktb + j) + lr) * 40 + 8 * lg);
        acc_s[j] = MF(qh, kv, acc_s[j]);
        acc_s[j] = MF(ql, kv, acc_s[j]);
      }
    }
  }

  __syncthreads();
#pragma unroll
  for (int j = 0; j < 5; j++)
#pragma unroll
    for (int r = 0; r < 4; r++) {
      int row = 16 * qt + 4 * lg + r;
      int col = 16 * (ktb + j) + lr;
      smf[row * 172 + col] = acc_s[j][r];
    }
  __syncthreads();

  {
    const int row = tid >> 3, l8 = tid & 7;
    int clo = row;          { int t2 = 64 - q0;            if (t2 > clo) clo = t2; }
    int chi = row + 128;    { int t2 = 2047 + 64 - q0;     if (t2 < chi) chi = t2; }
    float m = -1e30f;
    for (int c = l8; c < 160; c += 8)
      if (c >= clo && c <= chi) m = fmaxf(m, smf[row * 172 + c]);
    m = fmaxf(m, __shfl_xor(m, 1));
    m = fmaxf(m, __shfl_xor(m, 2));
    m = fmaxf(m, __shfl_xor(m, 4));
    float ssum = 0.f;
    for (int c = l8; c < 160; c += 8) {
      float e = (c >= clo && c <= chi) ? __expf(smf[row * 172 + c] - m) : 0.f;
      smf[row * 172 + c] = e;
      ssum += e;
    }
    ssum += __shfl_xor(ssum, 1);
    ssum += __shfl_xor(ssum, 2);
    ssum += __shfl_xor(ssum, 4);
    float rinv = 1.f / ssum;
    for (int c = l8; c < 160; c += 8)
      sm[PBF_O + row * 168 + c] = f2bf(smf[row * 172 + c] * rinv);
  }
  __syncthreads();

  const int dtl = (w & 1) * 2;
  bf16x8 pa[5];
#pragma unroll
  for (int ks = 0; ks < 5; ks++)
    pa[ks] = *(const bf16x8*)(sm + PBF_O + (16 * qt + lr) * 168 + 32 * ks + 8 * lg);

  for (int dc = 0; dc < 16; dc++) {
    const int d0 = dc * 64;
    uint4 vr[5];
#pragma unroll
    for (int i = 0; i < 5; i++) {
      int slot = i * 256 + tid;
      int k = slot >> 3, g = slot & 7;
      int kk = q0 - 64 + k;
      kk = kk < 0 ? 0 : (kk > 2047 ? 2047 : kk);
      vr[i] = *(const uint4*)(reprB + baseR + (size_t)kk * 1024 + d0 + 8 * g);
    }
    __syncthreads();
#pragma unroll
    for (int i = 0; i < 5; i++) {
      int slot = i * 256 + tid;
      int k = slot >> 3, g = slot & 7;
      const unsigned short* pv = (const unsigned short*)&vr[i];
#pragma unroll
      for (int j2 = 0; j2 < 8; j2++)
        sm[VT_O + (8 * g + j2) * 168 + k] = pv[j2];
    }
    __syncthreads();
    f32x4 ra0 = (f32x4){0.f, 0.f, 0.f, 0.f};
    f32x4 ra1 = (f32x4){0.f, 0.f, 0.f, 0.f};
#pragma unroll
    for (int ks = 0; ks < 5; ks++) {
      bf16x8 v0 = *(const bf16x8*)(sm + VT_O + (16 * dtl + lr) * 168 + 32 * ks + 8 * lg);
      bf16x8 v1 = *(const bf16x8*)(sm + VT_O + (16 * (dtl + 1) + lr) * 168 + 32 * ks + 8 * lg);
      ra0 = MF(pa[ks], v0, ra0);
      ra1 = MF(pa[ks], v1, ra1);
    }
#pragma unroll
    for (int r = 0; r < 4; r++) {
      int qg = q0 + 16 * qt + 4 * lg + r;
      size_t base = baseR + (size_t)qg * 1024 + d0;
      int dg0 = 16 * dtl + lr, dg1 = 16 * (dtl + 1) + lr;
      float o0 = bfu(reprB[base + dg0]) + fmaxf(ra0[r], 0.f);
      float o1 = bfu(reprB[base + dg1]) + fmaxf(ra1[r], 0.f);
      outB[base + dg0] = f2bf(o0);
      outB[base + dg1] = f2bf(o1);
    }
  }
}

// ---------------------------------------------------------------------------
// fp32-data MFMA kernel, R7: 512 threads / 8 waves -> 16 waves/CU (4/SIMD).
// Wave decomposition:
//  d-loop: wave = (qd = w&1 q-tile, eh = w>>1 e-32-group). Each wave computes
//          [16 q] x [32 e] of the Q-chunk; B-frags duplicated across q-tiles
//          (Wf is L2-hot; LDS A-read traffic per CU unchanged).
//  A3:     wave = (qt = w>>2, kg = w&3); key-tiles j in {kg, kg+4, kg+8<10}.
//  PV:     wave = (qt = w>>2, dt = w&3); one 16-d tile per wave.
//  softmax: 16 lanes per query row.
// LDS layout identical to R5/R6 (43008 B -> 2 blocks/CU by LDS and by grid).
// ---------------------------------------------------------------------------
#define FRQB(k)  ((k) * 4608)
#define FRKH_O  0
#define FRKL_O  6400
#define FQHI_O  12800
#define FQLO_O  17152
#define FPBF_O  12288
#define FVT_O   0
#define FSMEMU  21504

// Swizzled VT index: row in [0,64), k in [0,160). 16B-granule XOR.
__device__ __forceinline__ int vtidx(int row, int k) {
  int m = (row ^ (row >> 2)) & 7;
  return FVT_O + row * 192 + ((((k >> 3) ^ m) << 3) | (k & 7));
}

__global__ void __launch_bounds__(512, 4) attn_mfma_f32(
    const float* __restrict__ reprF,
    const unsigned short* __restrict__ WfH,
    const unsigned short* __restrict__ WfL,
    float* __restrict__ outF) {
  if (data_is_bf16((const unsigned short*)reprF)) return;   // bf16 data -> other kernel

  __shared__ alignas(16) unsigned short sm[FSMEMU];
  float* smf = (float*)sm;

  const int tid = threadIdx.x;
  const int w = tid >> 6, l = tid & 63, lr = l & 15, lg = l >> 4;
  const int b = blockIdx.y, q0 = blockIdx.x * 32;
  const size_t baseR = (size_t)b * 2048 * 1024;

  const int qd = w & 1, eh = w >> 1;       // d-loop: q-tile, e-32-group
  const int qt = w >> 2, kg = w & 3;       // A3/PV: q-tile, key-group/d-tile
  const int nj = (kg < 2) ? 3 : 2;         // key-tiles for this wave (j=kg+4jx)
  const int dt = w & 3;                    // PV d-16-tile

  const int rrow = tid >> 4, rcf = tid & 15;   // RQ staging: 32 rows x 16x16B

  f32x4 acc_s[3];
#pragma unroll
  for (int j = 0; j < 3; j++) acc_s[j] = (f32x4){0.f, 0.f, 0.f, 0.f};

  // ---------------- Phase A: Q = R@Wt (hi/lo 3-term) + S accumulate --------
  for (int ec = 0; ec < 8; ec++) {
    const int e0 = ec * 128;
    const int ecw8 = 8 * ec + 2 * eh;   // R16 base for this wave's B-frags
    f32x4 acc_q[2];
#pragma unroll
    for (int i = 0; i < 2; i++) acc_q[i] = (f32x4){0.f, 0.f, 0.f, 0.f};

    bf16x8 Bf[3][8];     // [rotation][2*et+h (hi) | 4+2*et+h (lo)]
    float4 rqv[2];       // [stage&1] — Q-row fp32 in flight (1 float4/thread)

#define LDB(bidx, sidx) {                                                      \
    size_t f00 = (((size_t)(ecw8 + 0) << 5) + 2 * (sidx) + 0) * 512 + l * 8;   \
    size_t f01 = (((size_t)(ecw8 + 0) << 5) + 2 * (sidx) + 1) * 512 + l * 8;   \
    size_t f10 = (((size_t)(ecw8 + 1) << 5) + 2 * (sidx) + 0) * 512 + l * 8;   \
    size_t f11 = (((size_t)(ecw8 + 1) << 5) + 2 * (sidx) + 1) * 512 + l * 8;   \
    Bf[bidx][0] = *(const bf16x8*)(WfH + f00);                                 \
    Bf[bidx][1] = *(const bf16x8*)(WfH + f01);                                 \
    Bf[bidx][2] = *(const bf16x8*)(WfH + f10);                                 \
    Bf[bidx][3] = *(const bf16x8*)(WfH + f11);                                 \
    Bf[bidx][4] = *(const bf16x8*)(WfL + f00);                                 \
    Bf[bidx][5] = *(const bf16x8*)(WfL + f01);                                 \
    Bf[bidx][6] = *(const bf16x8*)(WfL + f10);                                 \
    Bf[bidx][7] = *(const bf16x8*)(WfL + f11);                                 \
  }

#define WQ(sidx) {                                                             \
    const int wb = FRQB((sidx) & 1);                                           \
    ushort4 h4, l4;                                                            \
    float4 v = rqv[(sidx) & 1];                                                \
    hilo(v.x, h4.x, l4.x); hilo(v.y, h4.y, l4.y);                              \
    hilo(v.z, h4.z, l4.z); hilo(v.w, h4.w, l4.w);                              \
    *(ushort4*)(sm + wb + rrow * 72 + 4 * rcf) = h4;                           \
    *(ushort4*)(sm + wb + 2304 + rrow * 72 + 4 * rcf) = l4;                    \
  }

    // prologue: rq(0), rq(1), B(0), B(1) in flight
    rqv[0] = *(const float4*)(reprF + baseR + (size_t)(q0 + rrow) * 1024 + 0 + 4 * rcf);
    rqv[1] = *(const float4*)(reprF + baseR + (size_t)(q0 + rrow) * 1024 + 64 + 4 * rcf);
    LDB(0, 0)
    LDB(1, 1)

    __syncthreads();        // RQ-buf writes vs prev-ec A3 RK reads
    WQ(0)
    __syncthreads();        // write(0) visible

#pragma unroll
    for (int s = 0; s < 16; s++) {
      if (s < 15) WQ(s + 1)                 // buf[(s+1)&1]; data issued earlier
      if (s < 14) {                          // issue rq(s+2) -> rqv[s&1]
        const int d0n = 64 * (s + 2);
        rqv[s & 1] = *(const float4*)(reprF + baseR + (size_t)(q0 + rrow) * 1024 + d0n + 4 * rcf);
        LDB((s + 2) % 3, s + 2)              // issue B(s+2)
      }
      // compute(s): A from buf[s&1], B from Bf[s%3]
      {
        const int rqb = FRQB(s & 1);
#pragma unroll
        for (int h = 0; h < 2; h++) {
          bf16x8 ah = *(const bf16x8*)(sm + rqb + (16 * qd + lr) * 72 + 32 * h + 8 * lg);
          bf16x8 al = *(const bf16x8*)(sm + rqb + 2304 + (16 * qd + lr) * 72 + 32 * h + 8 * lg);
#pragma unroll
          for (int et = 0; et < 2; et++) {
            bf16x8 bh = Bf[s % 3][2 * et + h];
            bf16x8 bl = Bf[s % 3][4 + 2 * et + h];
            acc_q[et] = MF(ah, bh, acc_q[et]);
            acc_q[et] = MF(ah, bl, acc_q[et]);
            acc_q[et] = MF(al, bh, acc_q[et]);
          }
        }
      }
      __syncthreads();     // one barrier per stage
    }
#undef LDB
#undef WQ

    // issue RK loads for es=0 before the A2 VALU pass (latency hides under it)
    float4 rk4[3];
#pragma unroll
    for (int i = 0; i < 3; i++) {
      int slot = i * 512 + tid;
      if (slot < 1280) {
        int row = slot >> 3;
        int kk = q0 - 64 + row;
        kk = kk < 0 ? 0 : (kk > 2047 ? 2047 : kk);
        rk4[i] = *(const float4*)(reprF + baseR + (size_t)kk * 1024 + e0 + 4 * (slot & 7));
      }
    }

    // A2: Q accumulators -> QHI/QLO (hi/lo bf16 split)
#pragma unroll
    for (int et = 0; et < 2; et++)
#pragma unroll
      for (int r = 0; r < 4; r++) {
        int row = 16 * qd + 4 * lg + r;
        int col = 32 * eh + 16 * et + lr;
        float v = acc_q[et][r];
        unsigned short hi, lo;
        hilo(v, hi, lo);
        sm[FQHI_O + row * 136 + col] = hi;
        sm[FQLO_O + row * 136 + col] = lo;
      }

    // A3: S += Qchunk @ K^T (hi/lo 3-term), 4 e-slices of 32, pipelined
    for (int es = 0; es < 4; es++) {
      __syncthreads();   // RK writes vs d-loop buf reads / prev RK reads; A2 visible
#pragma unroll
      for (int i = 0; i < 3; i++) {
        int slot = i * 512 + tid;
        if (slot < 1280) {
          int row = slot >> 3, cf = slot & 7;
          ushort4 h4, l4;
          hilo(rk4[i].x, h4.x, l4.x); hilo(rk4[i].y, h4.y, l4.y);
          hilo(rk4[i].z, h4.z, l4.z); hilo(rk4[i].w, h4.w, l4.w);
          *(ushort4*)(sm + FRKH_O + row * 40 + 4 * cf) = h4;
          *(ushort4*)(sm + FRKL_O + row * 40 + 4 * cf) = l4;
        }
      }
      __syncthreads();
      if (es < 3) {
#pragma unroll
        for (int i = 0; i < 3; i++) {
          int slot = i * 512 + tid;
          if (slot < 1280) {
            int row = slot >> 3;
            int kk = q0 - 64 + row;
            kk = kk < 0 ? 0 : (kk > 2047 ? 2047 : kk);
            rk4[i] = *(const float4*)(reprF + baseR + (size_t)kk * 1024 + e0 + 32 * (es + 1) + 4 * (slot & 7));
          }
        }
      }
      bf16x8 qh = *(const bf16x8*)(sm + FQHI_O + (16 * qt + lr) * 136 + 32 * es + 8 * lg);
      bf16x8 ql = *(const bf16x8*)(sm + FQLO_O + (16 * qt + lr) * 136 + 32 * es + 8 * lg);
#pragma unroll
      for (int jx = 0; jx < 3; jx++) {
        if (jx < nj) {
          int jj = kg + 4 * jx;
          bf16x8 kh = *(const bf16x8*)(sm + FRKH_O + (16 * jj + lr) * 40 + 8 * lg);
          bf16x8 kl = *(const bf16x8*)(sm + FRKL_O + (16 * jj + lr) * 40 + 8 * lg);
          acc_s[jx] = MF(qh, kh, acc_s[jx]);
          acc_s[jx] = MF(qh, kl, acc_s[jx]);
          acc_s[jx] = MF(ql, kh, acc_s[jx]);
        }
      }
    }
  }

  __syncthreads();
  // scores -> Sls (f32, pitch 172) @0 (RK/RQ dead)
#pragma unroll
  for (int jx = 0; jx < 3; jx++) {
    if (jx < nj) {
      int jj = kg + 4 * jx;
#pragma unroll
      for (int r = 0; r < 4; r++) {
        int row = 16 * qt + 4 * lg + r;
        int col = 16 * jj + lr;
        smf[row * 172 + col] = acc_s[jx][r];
      }
    }
  }
  __syncthreads();

  // masked softmax (16 lanes/row), probs -> PBF bf16 (@12288, over QHI dead)
  {
    const int row = tid >> 4, l16 = tid & 15;
    int clo = row;          { int t2 = 64 - q0;            if (t2 > clo) clo = t2; }
    int chi = row + 128;    { int t2 = 2047 + 64 - q0;     if (t2 < chi) chi = t2; }
    float m = -1e30f;
    for (int c = l16; c < 160; c += 16)
      if (c >= clo && c <= chi) m = fmaxf(m, smf[row * 172 + c]);
    m = fmaxf(m, __shfl_xor(m, 1));
    m = fmaxf(m, __shfl_xor(m, 2));
    m = fmaxf(m, __shfl_xor(m, 4));
    m = fmaxf(m, __shfl_xor(m, 8));
    float ssum = 0.f;
    for (int c = l16; c < 160; c += 16) {
      float e = (c >= clo && c <= chi) ? __expf(smf[row * 172 + c] - m) : 0.f;
      smf[row * 172 + c] = e;
      ssum += e;
    }
    ssum += __shfl_xor(ssum, 1);
    ssum += __shfl_xor(ssum, 2);
    ssum += __shfl_xor(ssum, 4);
    ssum += __shfl_xor(ssum, 8);
    float rinv = 1.f / ssum;
    for (int c = l16; c < 160; c += 16)
      sm[FPBF_O + row * 168 + c] = f2bf(smf[row * 172 + c] * rinv);
  }
  __syncthreads();

  // ---------------- Phase B: ra = P @ V (single-bf16), out = repr+relu -----
  bf16x8 pa[5];
#pragma unroll
  for (int ks = 0; ks < 5; ks++)
    pa[ks] = *(const bf16x8*)(sm + FPBF_O + (16 * qt + lr) * 168 + 32 * ks + 8 * lg);

  float4 vr4[5];
  // prologue: issue dc=0 V loads (160x64 f32 = 2560 float4 / 512 thr = 5 ea)
#pragma unroll
  for (int i = 0; i < 5; i++) {
    int slot = i * 512 + tid;
    int k = slot >> 4, g = slot & 15;
    int kk = q0 - 64 + k;
    kk = kk < 0 ? 0 : (kk > 2047 ? 2047 : kk);
    vr4[i] = *(const float4*)(reprF + baseR + (size_t)kk * 1024 + 4 * g);
  }

  for (int dc = 0; dc < 16; dc++) {
    const int d0 = dc * 64;
    __syncthreads();   // previous chunk's VT reads done (dc=0: Sls dead)
#pragma unroll
    for (int i = 0; i < 5; i++) {
      int slot = i * 512 + tid;
      int k = slot >> 4, g = slot & 15;
      sm[vtidx(4 * g + 0, k)] = f2bf(vr4[i].x);
      sm[vtidx(4 * g + 1, k)] = f2bf(vr4[i].y);
      sm[vtidx(4 * g + 2, k)] = f2bf(vr4[i].z);
      sm[vtidx(4 * g + 3, k)] = f2bf(vr4[i].w);
    }
    __syncthreads();
    if (dc < 15) {
      const int d0n = d0 + 64;
#pragma unroll
      for (int i = 0; i < 5; i++) {
        int slot = i * 512 + tid;
        int k = slot >> 4, g = slot & 15;
        int kk = q0 - 64 + k;
        kk = kk < 0 ? 0 : (kk > 2047 ? 2047 : kk);
        vr4[i] = *(const float4*)(reprF + baseR + (size_t)kk * 1024 + d0n + 4 * g);
      }
    }
    f32x4 ra0 = (f32x4){0.f, 0.f, 0.f, 0.f};
    const int row0 = 16 * dt + lr;
#pragma unroll
    for (int ks = 0; ks < 5; ks++) {
      bf16x8 v0 = *(const bf16x8*)(sm + vtidx(row0, 32 * ks + 8 * lg));
      ra0 = MF(pa[ks], v0, ra0);
    }
#pragma unroll
    for (int r = 0; r < 4; r++) {
      int qg = q0 + 16 * qt + 4 * lg + r;
      size_t base = baseR + (size_t)qg * 1024 + d0;
      int dg0 = 16 * dt + lr;
      outF[base + dg0] = reprF[base + dg0] + fmaxf(ra0[r], 0.f);
    }
  }
}

extern "C" void kernel_launch(void* const* d_in, const int* in_sizes, int n_in,
                              void* d_out, int out_size, void* d_ws, size_t ws_size,
                              hipStream_t stream) {
  const void* repr = d_in[0];
  const void* W    = d_in[1];
  dim3 grid(SEQL / QT, NB);   // (64, 8) = 512 blocks

  const bool use_mfma = (d_ws != nullptr) && (ws_size >= (size_t)4 * 1024 * 1024);
  if (use_mfma) {
    tposeW2<<<dim3(256), dim3(256), 0, stream>>>(repr, W, d_ws);
    attn_mfma<<<grid, dim3(256), 0, stream>>>(
        (const unsigned short*)repr, (const unsigned short*)d_ws, (unsigned short*)d_out);
    attn_mfma_f32<<<grid, dim3(512), 0, stream>>>(
        (const float*)repr, (const unsigned short*)d_ws,
        (const unsigned short*)d_ws + (1u << 20), (float*)d_out);
  } else {
    attn_fused<true><<<grid, dim3(256), 0, stream>>>(repr, W, d_out);
    attn_fused<false><<<grid, dim3(256), 0, stream>>>(repr, W, d_out);
  }
}

// Round 8
// 340.690 us; speedup vs baseline: 1.2851x; 1.2851x over previous
//
#include <hip/hip_runtime.h>

// AttentionWindow: out = repr + relu(softmax_masked((repr@W)@repr^T) @ repr)
// BATCH=8, SEQ=2048, HIDDEN=1024, window half-width 64 (|i-j|>64 masked).
//
// Modes (uniform data sniff):
//   bf16 data  -> attn_mfma      (verified; unchanged, 256 thr)
//   fp32 data  -> attn_mfma_f32  (R8: inverted loop nest — one RQ staging
//                                 feeds ALL e-columns; d-loop 128->32 fat
//                                 phases (96 MFMA/wave each); K fragments
//                                 global->register (no RK staging barriers);
//                                 ~83 total barriers vs ~210)
//   no workspace -> proven VALU pair.

#define SEQL 2048
#define HID  1024
#define NB   8
#define QT   32
#define KT   160
#define DCO  128
#define EC   32
#define DS   32
#define RP   36
#define WP   132
#define QP   132
#define KP   36
#define SP   161

#define RS_OFF  0
#define WS_OFF  1152
#define KS_OFF  0
#define QCS_OFF 5760
#define SC_OFF  5760
#define SMEM_F  10912

__device__ __forceinline__ float bfu(unsigned int lo16) {
  union { unsigned int i; float f; } v; v.i = lo16 << 16; return v.f;
}
__device__ __forceinline__ unsigned short f2bf(float f) {
  union { float f; unsigned int i; } v; v.f = f;
  unsigned int r = v.i + 0x7FFFu + ((v.i >> 16) & 1u);   // RNE
  return (unsigned short)(r >> 16);
}
__device__ __forceinline__ void hilo(float v, unsigned short& h, unsigned short& l) {
  h = f2bf(v);
  l = f2bf(v - bfu(h));
}

// Uniform dtype sniff (thread-invariant).
__device__ bool data_is_bf16(const unsigned short* u) {
  int cnt = 0;
  for (int i = 0; i < 256; i++) {
    int e = (u[i] >> 7) & 0xFF;
    if (e >= 107 && e <= 131) cnt++;
  }
  return cnt >= 230;
}

template<bool BF16>
__device__ __forceinline__ float4 ld4(const void* p, size_t idx) {
  if (BF16) {
    uint2 u = *(const uint2*)((const unsigned short*)p + idx);
    float4 r;
    r.x = bfu(u.x & 0xFFFFu); r.y = bfu(u.x >> 16);
    r.z = bfu(u.y & 0xFFFFu); r.w = bfu(u.y >> 16);
    return r;
  } else {
    return *(const float4*)((const float*)p + idx);
  }
}

template<bool BF16>
__device__ __forceinline__ void st4(void* p, size_t idx, float4 v) {
  if (BF16) {
    ushort4 o;
    o.x = f2bf(v.x); o.y = f2bf(v.y); o.z = f2bf(v.z); o.w = f2bf(v.w);
    *(ushort4*)((unsigned short*)p + idx) = o;
  } else {
    *(float4*)((float*)p + idx) = v;
  }
}

__device__ __forceinline__ void fma4(float4& q, float a, const float4& w) {
  q.x += a * w.x; q.y += a * w.y; q.z += a * w.z; q.w += a * w.w;
}

// ---------------------------------------------------------------------------
// OLD proven VALU kernel (fallback when no workspace)
// ---------------------------------------------------------------------------
template<bool BF16>
__global__ void __launch_bounds__(256) attn_fused(
    const void* __restrict__ reprv, const void* __restrict__ Wv,
    void* __restrict__ outv) {
  if (data_is_bf16((const unsigned short*)reprv) != BF16) return;

  __shared__ float smem[SMEM_F];
  const int tid = threadIdx.x;
  const int b = blockIdx.y;
  const int q0 = blockIdx.x * QT;
  const size_t baseR = (size_t)b * SEQL * HID;

  const int tx = tid & 31, ty = tid >> 5;

  float acc[4][5];
#pragma unroll
  for (int i = 0; i < 4; i++)
#pragma unroll
    for (int j = 0; j < 5; j++) acc[i][j] = 0.f;

  for (int d0 = 0; d0 < HID; d0 += DCO) {
    float4 qc[4];
#pragma unroll
    for (int i = 0; i < 4; i++) qc[i] = make_float4(0.f, 0.f, 0.f, 0.f);

    for (int e0 = 0; e0 < HID; e0 += EC) {
      {
        int row = tid >> 3, cg = tid & 7;
        float4 v = ld4<BF16>(reprv, baseR + (size_t)(q0 + row) * HID + e0 + 4 * cg);
        *(float4*)&smem[RS_OFF + row * RP + 4 * cg] = v;
      }
#pragma unroll
      for (int i2 = 0; i2 < 4; i2++) {
        int f = i2 * 256 + tid;
        int row = f >> 5, cg = f & 31;
        float4 v = ld4<BF16>(Wv, (size_t)(e0 + row) * HID + d0 + 4 * cg);
        *(float4*)&smem[WS_OFF + row * WP + 4 * cg] = v;
      }
      __syncthreads();
#pragma unroll
      for (int ee = 0; ee < EC; ee += 4) {
        float4 rv[4];
#pragma unroll
        for (int i = 0; i < 4; i++)
          rv[i] = *(const float4*)&smem[RS_OFF + (ty + 8 * i) * RP + ee];
        {
          float4 wv = *(const float4*)&smem[WS_OFF + (ee + 0) * WP + 4 * tx];
          fma4(qc[0], rv[0].x, wv); fma4(qc[1], rv[1].x, wv);
          fma4(qc[2], rv[2].x, wv); fma4(qc[3], rv[3].x, wv);
        }
        {
          float4 wv = *(const float4*)&smem[WS_OFF + (ee + 1) * WP + 4 * tx];
          fma4(qc[0], rv[0].y, wv); fma4(qc[1], rv[1].y, wv);
          fma4(qc[2], rv[2].y, wv); fma4(qc[3], rv[3].y, wv);
        }
        {
          float4 wv = *(const float4*)&smem[WS_OFF + (ee + 2) * WP + 4 * tx];
          fma4(qc[0], rv[0].z, wv); fma4(qc[1], rv[1].z, wv);
          fma4(qc[2], rv[2].z, wv); fma4(qc[3], rv[3].z, wv);
        }
        {
          float4 wv = *(const float4*)&smem[WS_OFF + (ee + 3) * WP + 4 * tx];
          fma4(qc[0], rv[0].w, wv); fma4(qc[1], rv[1].w, wv);
          fma4(qc[2], rv[2].w, wv); fma4(qc[3], rv[3].w, wv);
        }
      }
      __syncthreads();
    }

#pragma unroll
    for (int i = 0; i < 4; i++)
      *(float4*)&smem[QCS_OFF + (ty + 8 * i) * QP + 4 * tx] = qc[i];

    for (int s = 0; s < DCO; s += DS) {
#pragma unroll
      for (int i2 = 0; i2 < 5; i2++) {
        int f = i2 * 256 + tid;
        int row = f >> 3, cg = f & 7;
        int kk = q0 - 64 + row;
        kk = kk < 0 ? 0 : (kk > SEQL - 1 ? SEQL - 1 : kk);
        float4 v = ld4<BF16>(reprv, baseR + (size_t)kk * HID + d0 + s + 4 * cg);
        *(float4*)&smem[KS_OFF + row * KP + 4 * cg] = v;
      }
      __syncthreads();
#pragma unroll
      for (int dd = 0; dd < DS; dd += 4) {
        float4 qv[4];
#pragma unroll
        for (int i = 0; i < 4; i++)
          qv[i] = *(const float4*)&smem[QCS_OFF + (ty + 8 * i) * QP + s + dd];
#pragma unroll
        for (int j = 0; j < 5; j++) {
          float4 kv = *(const float4*)&smem[KS_OFF + (tx + 32 * j) * KP + dd];
#pragma unroll
          for (int i = 0; i < 4; i++)
            acc[i][j] += qv[i].x * kv.x + qv[i].y * kv.y + qv[i].z * kv.z + qv[i].w * kv.w;
        }
      }
      __syncthreads();
    }
  }

#pragma unroll
  for (int i = 0; i < 4; i++)
#pragma unroll
    for (int j = 0; j < 5; j++)
      smem[SC_OFF + (ty + 8 * i) * SP + tx + 32 * j] = acc[i][j];
  __syncthreads();

  {
    const int row = tid >> 3, l8 = tid & 7;
    int clo = row;          { int t = 64 - q0;            if (t > clo) clo = t; }
    int chi = row + 128;    { int t = SEQL - 1 + 64 - q0; if (t < chi) chi = t; }
    float m = -1e30f;
    for (int c = l8; c < KT; c += 8)
      if (c >= clo && c <= chi) m = fmaxf(m, smem[SC_OFF + row * SP + c]);
    m = fmaxf(m, __shfl_xor(m, 1));
    m = fmaxf(m, __shfl_xor(m, 2));
    m = fmaxf(m, __shfl_xor(m, 4));
    float ssum = 0.f;
    for (int c = l8; c < KT; c += 8) {
      float e = (c >= clo && c <= chi) ? __expf(smem[SC_OFF + row * SP + c] - m) : 0.f;
      smem[SC_OFF + row * SP + c] = e;
      ssum += e;
    }
    ssum += __shfl_xor(ssum, 1);
    ssum += __shfl_xor(ssum, 2);
    ssum += __shfl_xor(ssum, 4);
    float rinv = 1.f / ssum;
    for (int c = l8; c < KT; c += 8) smem[SC_OFF + row * SP + c] *= rinv;
  }
  __syncthreads();

  const int rr = tid >> 3, dq = tid & 7;
  for (int d0 = 0; d0 < HID; d0 += DS) {
#pragma unroll
    for (int i2 = 0; i2 < 5; i2++) {
      int f = i2 * 256 + tid;
      int row = f >> 3, cg = f & 7;
      int kk = q0 - 64 + row;
      kk = kk < 0 ? 0 : (kk > SEQL - 1 ? SEQL - 1 : kk);
      float4 v = ld4<BF16>(reprv, baseR + (size_t)kk * HID + d0 + 4 * cg);
      *(float4*)&smem[KS_OFF + row * KP + 4 * cg] = v;
    }
    __syncthreads();
    float4 o = make_float4(0.f, 0.f, 0.f, 0.f);
#pragma unroll 4
    for (int c = 0; c < KT; c++) {
      float4 kv = *(const float4*)&smem[KS_OFF + c * KP + 4 * dq];
      float p = smem[SC_OFF + rr * SP + c];
      o.x += p * kv.x; o.y += p * kv.y; o.z += p * kv.z; o.w += p * kv.w;
    }
    size_t goff = baseR + (size_t)(q0 + rr) * HID + d0 + 4 * dq;
    float4 rv = ld4<BF16>(reprv, goff);
    float4 ov;
    ov.x = rv.x + fmaxf(o.x, 0.f);
    ov.y = rv.y + fmaxf(o.y, 0.f);
    ov.z = rv.z + fmaxf(o.z, 0.f);
    ov.w = rv.w + fmaxf(o.w, 0.f);
    st4<BF16>(outv, goff, ov);
    __syncthreads();
  }
}

// ---------------------------------------------------------------------------
// MFMA common
// ---------------------------------------------------------------------------
typedef float f32x4 __attribute__((ext_vector_type(4)));
typedef short bf16x8 __attribute__((ext_vector_type(8)));

#define MF(a_, b_, c_) __builtin_amdgcn_mfma_f32_16x16x32_bf16((a_), (b_), (c_), 0, 0, 0)

// LDS-only barrier: drains this wave's LDS ops then raw s_barrier —
// global loads stay in flight across it (T4 pattern; measured safe in R6).
__device__ __forceinline__ void bar_lgkm() {
  asm volatile("s_waitcnt lgkmcnt(0)" ::: "memory");
  __builtin_amdgcn_s_barrier();
}

// Convert 8 fp32 (two float4) to hi/lo bf16x8 (register-only).
__device__ __forceinline__ void cvt8(const float4 a, const float4 b,
                                     bf16x8& h8, bf16x8& l8) {
  unsigned short h, lo_;
  hilo(a.x, h, lo_); h8[0] = (short)h; l8[0] = (short)lo_;
  hilo(a.y, h, lo_); h8[1] = (short)h; l8[1] = (short)lo_;
  hilo(a.z, h, lo_); h8[2] = (short)h; l8[2] = (short)lo_;
  hilo(a.w, h, lo_); h8[3] = (short)h; l8[3] = (short)lo_;
  hilo(b.x, h, lo_); h8[4] = (short)h; l8[4] = (short)lo_;
  hilo(b.y, h, lo_); h8[5] = (short)h; l8[5] = (short)lo_;
  hilo(b.z, h, lo_); h8[6] = (short)h; l8[6] = (short)lo_;
  hilo(b.w, h, lo_); h8[7] = (short)h; l8[7] = (short)lo_;
}

// W-transpose (dual-mode).
//  bf16 data: Wt bf16 linear [e][d] @ws0 (2MB, exact) — for attn_mfma.
//  fp32 data: FRAGMENT-ordered hi/lo split for direct global->register
//    B-operand loads: dest_ush(e,d) =
//      (((e>>4)<<5)|(d>>5))*512 + ((((d>>3)&3)<<4)|(e&15))*8 + (d&7)
//    WfH @ws0 (2MB), WfL @ws+2MB.
__global__ void __launch_bounds__(256) tposeW2(
    const void* __restrict__ reprv, const void* __restrict__ Wv,
    void* __restrict__ wsv) {
  const bool isbf = data_is_bf16((const unsigned short*)reprv);
  __shared__ alignas(16) unsigned char twsb[64 * 68 * 4];
  const int t = threadIdx.x;
  const int d0 = (blockIdx.x & 15) * 64, e0 = (blockIdx.x >> 4) * 64;
  if (isbf) {
    unsigned short* tl = (unsigned short*)twsb;
    const unsigned short* WB = (const unsigned short*)Wv;
    unsigned short* WtB = (unsigned short*)wsv;
#pragma unroll
    for (int i = 0; i < 2; i++) {
      int slot = i * 256 + t, row = slot >> 3, c8 = slot & 7;
      *(uint4*)(tl + row * 72 + 8 * c8) =
          *(const uint4*)(WB + (size_t)(d0 + row) * 1024 + e0 + 8 * c8);
    }
    __syncthreads();
#pragma unroll
    for (int i = 0; i < 2; i++) {
      int slot = i * 256 + t, er = slot >> 3, c8 = slot & 7;
      unsigned short v[8];
#pragma unroll
      for (int j = 0; j < 8; j++) v[j] = tl[(8 * c8 + j) * 72 + er];
      *(uint4*)(WtB + (size_t)(e0 + er) * 1024 + d0 + 8 * c8) = *(const uint4*)v;
    }
  } else {
    float* tlf = (float*)twsb;
    const float* WF = (const float*)Wv;
    unsigned short* WfH = (unsigned short*)wsv;
    unsigned short* WfL = WfH + (1u << 20);   // +2 MB
#pragma unroll
    for (int i = 0; i < 4; i++) {
      int slot = i * 256 + t, row = slot >> 4, cf = slot & 15;
      *(float4*)&tlf[row * 68 + 4 * cf] =
          *(const float4*)(WF + (size_t)(d0 + row) * 1024 + e0 + 4 * cf);
    }
    __syncthreads();
#pragma unroll
    for (int i = 0; i < 2; i++) {
      int slot = i * 256 + t, er = slot >> 3, c8 = slot & 7;
      int e = e0 + er;
      int dg = d0 + 8 * c8;
      unsigned short vh[8], vl[8];
#pragma unroll
      for (int j = 0; j < 8; j++) {
        float v = tlf[(8 * c8 + j) * 68 + er];
        hilo(v, vh[j], vl[j]);
      }
      size_t dst = (size_t)(((e >> 4) << 5) | (dg >> 5)) * 512
                 + (size_t)(((((dg >> 3) & 3) << 4) | (e & 15))) * 8;
      *(uint4*)(WfH + dst) = *(const uint4*)vh;
      *(uint4*)(WfL + dst) = *(const uint4*)vl;
    }
  }
}

// ---------------------------------------------------------------------------
// bf16-data MFMA kernel (round-1 verified, unchanged, 256 threads)
// ---------------------------------------------------------------------------
#define WTS_O 0
#define RQS_O 9216
#define RK_O  11520
#define QHI_O 17920
#define QLO_O 22272
#define PBF_O 11008
#define VT_O  16384
#define SMEMU 27136

__global__ void __launch_bounds__(256, 2) attn_mfma(
    const unsigned short* __restrict__ reprB,
    const unsigned short* __restrict__ WtB,
    unsigned short* __restrict__ outB) {
  if (!data_is_bf16(reprB)) return;

  __shared__ alignas(16) unsigned short sm[SMEMU];
  float* smf = (float*)sm;

  const int tid = threadIdx.x;
  const int w = tid >> 6, l = tid & 63, lr = l & 15, lg = l >> 4;
  const int b = blockIdx.y, q0 = blockIdx.x * 32;
  const size_t baseR = (size_t)b * 2048 * 1024;
  const int qt = w >> 1;
  const int ktb = (w & 1) * 5;

  f32x4 acc_s[5];
#pragma unroll
  for (int j = 0; j < 5; j++) acc_s[j] = (f32x4){0.f, 0.f, 0.f, 0.f};

  for (int ec = 0; ec < 8; ec++) {
    const int e0 = ec * 128;
    f32x4 acc_q[2][2];
#pragma unroll
    for (int i = 0; i < 2; i++)
#pragma unroll
      for (int j = 0; j < 2; j++) acc_q[i][j] = (f32x4){0.f, 0.f, 0.f, 0.f};

    for (int s = 0; s < 16; s++) {
      const int d0 = s * 64;
      uint4 wtr[4], rqr;
#pragma unroll
      for (int i = 0; i < 4; i++) {
        int slot = i * 256 + tid, row = slot >> 3, c8 = slot & 7;
        wtr[i] = *(const uint4*)(WtB + (size_t)(e0 + row) * 1024 + d0 + 8 * c8);
      }
      {
        int row = tid >> 3, c8 = tid & 7;
        rqr = *(const uint4*)(reprB + baseR + (size_t)(q0 + row) * 1024 + d0 + 8 * c8);
      }
      __syncthreads();
#pragma unroll
      for (int i = 0; i < 4; i++) {
        int slot = i * 256 + tid, row = slot >> 3, c8 = slot & 7;
        *(uint4*)(sm + WTS_O + row * 72 + 8 * c8) = wtr[i];
      }
      {
        int row = tid >> 3, c8 = tid & 7;
        *(uint4*)(sm + RQS_O + row * 72 + 8 * c8) = rqr;
      }
      __syncthreads();
#pragma unroll
      for (int h = 0; h < 2; h++) {
        bf16x8 a0 = *(const bf16x8*)(sm + RQS_O + (lr) * 72 + 32 * h + 8 * lg);
        bf16x8 a1 = *(const bf16x8*)(sm + RQS_O + (16 + lr) * 72 + 32 * h + 8 * lg);
        bf16x8 b0 = *(const bf16x8*)(sm + WTS_O + (32 * w + lr) * 72 + 32 * h + 8 * lg);
        bf16x8 b1 = *(const bf16x8*)(sm + WTS_O + (32 * w + 16 + lr) * 72 + 32 * h + 8 * lg);
        acc_q[0][0] = MF(a0, b0, acc_q[0][0]);
        acc_q[0][1] = MF(a0, b1, acc_q[0][1]);
        acc_q[1][0] = MF(a1, b0, acc_q[1][0]);
        acc_q[1][1] = MF(a1, b1, acc_q[1][1]);
      }
    }

#pragma unroll
    for (int qq = 0; qq < 2; qq++)
#pragma unroll
      for (int et = 0; et < 2; et++)
#pragma unroll
        for (int r = 0; r < 4; r++) {
          int row = 16 * qq + 4 * lg + r;
          int col = 32 * w + 16 * et + lr;
          float v = acc_q[qq][et][r];
          unsigned short hi = f2bf(v);
          sm[QHI_O + row * 136 + col] = hi;
          sm[QLO_O + row * 136 + col] = f2bf(v - bfu(hi));
        }

    for (int es = 0; es < 4; es++) {
      uint4 rkr[3];
#pragma unroll
      for (int i = 0; i < 3; i++) {
        int slot = i * 256 + tid;
        if (slot < 640) {
          int row = slot >> 2, c8 = slot & 3;
          int kk = q0 - 64 + row;
          kk = kk < 0 ? 0 : (kk > 2047 ? 2047 : kk);
          rkr[i] = *(const uint4*)(reprB + baseR + (size_t)kk * 1024 + e0 + 32 * es + 8 * c8);
        }
      }
      __syncthreads();
#pragma unroll
      for (int i = 0; i < 3; i++) {
        int slot = i * 256 + tid;
        if (slot < 640) {
          int row = slot >> 2, c8 = slot & 3;
          *(uint4*)(sm + RK_O + row * 40 + 8 * c8) = rkr[i];
        }
      }
      __syncthreads();
      bf16x8 qh = *(const bf16x8*)(sm + QHI_O + (16 * qt + lr) * 136 + 32 * es + 8 * lg);
      bf16x8 ql = *(const bf16x8*)(sm + QLO_O + (16 * qt + lr) * 136 + 32 * es + 8 * lg);
#pragma unroll
      for (int j = 0; j < 5; j++) {
        bf16x8 kv = *(const bf16x8*)(sm + RK_O + (16 * (ktb + j) + lr) * 40 + 8 * lg);
        acc_s[j] = MF(qh, kv, acc_s[j]);
        acc_s[j] = MF(ql, kv, acc_s[j]);
      }
    }
  }

  __syncthreads();
#pragma unroll
  for (int j = 0; j < 5; j++)
#pragma unroll
    for (int r = 0; r < 4; r++) {
      int row = 16 * qt + 4 * lg + r;
      int col = 16 * (ktb + j) + lr;
      smf[row * 172 + col] = acc_s[j][r];
    }
  __syncthreads();

  {
    const int row = tid >> 3, l8 = tid & 7;
    int clo = row;          { int t2 = 64 - q0;            if (t2 > clo) clo = t2; }
    int chi = row + 128;    { int t2 = 2047 + 64 - q0;     if (t2 < chi) chi = t2; }
    float m = -1e30f;
    for (int c = l8; c < 160; c += 8)
      if (c >= clo && c <= chi) m = fmaxf(m, smf[row * 172 + c]);
    m = fmaxf(m, __shfl_xor(m, 1));
    m = fmaxf(m, __shfl_xor(m, 2));
    m = fmaxf(m, __shfl_xor(m, 4));
    float ssum = 0.f;
    for (int c = l8; c < 160; c += 8) {
      float e = (c >= clo && c <= chi) ? __expf(smf[row * 172 + c] - m) : 0.f;
      smf[row * 172 + c] = e;
      ssum += e;
    }
    ssum += __shfl_xor(ssum, 1);
    ssum += __shfl_xor(ssum, 2);
    ssum += __shfl_xor(ssum, 4);
    float rinv = 1.f / ssum;
    for (int c = l8; c < 160; c += 8)
      sm[PBF_O + row * 168 + c] = f2bf(smf[row * 172 + c] * rinv);
  }
  __syncthreads();

  const int dtl = (w & 1) * 2;
  bf16x8 pa[5];
#pragma unroll
  for (int ks = 0; ks < 5; ks++)
    pa[ks] = *(const bf16x8*)(sm + PBF_O + (16 * qt + lr) * 168 + 32 * ks + 8 * lg);

  for (int dc = 0; dc < 16; dc++) {
    const int d0 = dc * 64;
    uint4 vr[5];
#pragma unroll
    for (int i = 0; i < 5; i++) {
      int slot = i * 256 + tid;
      int k = slot >> 3, g = slot & 7;
      int kk = q0 - 64 + k;
      kk = kk < 0 ? 0 : (kk > 2047 ? 2047 : kk);
      vr[i] = *(const uint4*)(reprB + baseR + (size_t)kk * 1024 + d0 + 8 * g);
    }
    __syncthreads();
#pragma unroll
    for (int i = 0; i < 5; i++) {
      int slot = i * 256 + tid;
      int k = slot >> 3, g = slot & 7;
      const unsigned short* pv = (const unsigned short*)&vr[i];
#pragma unroll
      for (int j2 = 0; j2 < 8; j2++)
        sm[VT_O + (8 * g + j2) * 168 + k] = pv[j2];
    }
    __syncthreads();
    f32x4 ra0 = (f32x4){0.f, 0.f, 0.f, 0.f};
    f32x4 ra1 = (f32x4){0.f, 0.f, 0.f, 0.f};
#pragma unroll
    for (int ks = 0; ks < 5; ks++) {
      bf16x8 v0 = *(const bf16x8*)(sm + VT_O + (16 * dtl + lr) * 168 + 32 * ks + 8 * lg);
      bf16x8 v1 = *(const bf16x8*)(sm + VT_O + (16 * (dtl + 1) + lr) * 168 + 32 * ks + 8 * lg);
      ra0 = MF(pa[ks], v0, ra0);
      ra1 = MF(pa[ks], v1, ra1);
    }
#pragma unroll
    for (int r = 0; r < 4; r++) {
      int qg = q0 + 16 * qt + 4 * lg + r;
      size_t base = baseR + (size_t)qg * 1024 + d0;
      int dg0 = 16 * dtl + lr, dg1 = 16 * (dtl + 1) + lr;
      float o0 = bfu(reprB[base + dg0]) + fmaxf(ra0[r], 0.f);
      float o1 = bfu(reprB[base + dg1]) + fmaxf(ra1[r], 0.f);
      outB[base + dg0] = f2bf(o0);
      outB[base + dg1] = f2bf(o1);
    }
  }
}

// ---------------------------------------------------------------------------
// fp32-data MFMA kernel, R8: inverted loop nest.
//  Two half-e passes (512 e each). Per half:
//   d-sweep: 16 stages over full d; ONE RQ staging feeds all 4 e-chunks of
//     the half (acc_q[4][2][2] = 64 VGPRs); B-frags global->reg (2-deep
//     prefetch); 96 MFMA/wave per stage; 1 lgkm-barrier per stage.
//   A3: per 128-e chunk: {bar; QS write from acc regs; bar; 4 e-slices with
//     K-frags loaded global->reg (3-deep rotation), 15 MFMA/wave each} —
//     no K staging barriers at all.
//  Softmax/PV unchanged (R6 256-thr versions).
//
// LDS (ush), phase-disjoint aliasing:
//  d-sweep: RQ dbuf: buf k @k*4608 (H 0..2304, L 2304..4608)   -> 0..9216
//  A3:      QSH [32][136] @9216..13568, QSL @13568..17920
//  epilog:  Sls f32 [32][172] @byte 0 (ush 0..11008; RQ/QS-overlap dead)
//           PBF [32][168] @12288..17664
//           VT  [64][192] @0..12288 (over Sls dead)
// Total 17920 ush = 35840 B.
// ---------------------------------------------------------------------------
#define FRQB(k)  ((k) * 4608)
#define FQSH_O  9216
#define FQSL_O  13568
#define FPBF_O  12288
#define FVT_O   0
#define FSMEMU  17920

// Swizzled VT index: row in [0,64), k in [0,160). 16B-granule XOR.
__device__ __forceinline__ int vtidx(int row, int k) {
  int m = (row ^ (row >> 2)) & 7;
  return FVT_O + row * 192 + ((((k >> 3) ^ m) << 3) | (k & 7));
}

__global__ void __launch_bounds__(256, 2) attn_mfma_f32(
    const float* __restrict__ reprF,
    const unsigned short* __restrict__ WfH,
    const unsigned short* __restrict__ WfL,
    float* __restrict__ outF) {
  if (data_is_bf16((const unsigned short*)reprF)) return;   // bf16 data -> other kernel

  __shared__ alignas(16) unsigned short sm[FSMEMU];
  float* smf = (float*)sm;

  const int tid = threadIdx.x;
  const int w = tid >> 6, l = tid & 63, lr = l & 15, lg = l >> 4;
  const int b = blockIdx.y, q0 = blockIdx.x * 32;
  const size_t baseR = (size_t)b * 2048 * 1024;
  const int qt = w >> 1, ktb = (w & 1) * 5;
  const int rrow = tid >> 4, rcf = tid & 15;   // RQ staging: 16 rows x 16x16B

  f32x4 acc_s[5];
#pragma unroll
  for (int j = 0; j < 5; j++) acc_s[j] = (f32x4){0.f, 0.f, 0.f, 0.f};

  for (int half = 0; half < 2; half++) {
    // ---------------- d-sweep: Q[32 q][512 e of this half] ----------------
    f32x4 acc_q[4][2][2];   // [ecq][qq][et]
#pragma unroll
    for (int q = 0; q < 4; q++)
#pragma unroll
      for (int i = 0; i < 2; i++)
#pragma unroll
        for (int j = 0; j < 2; j++) acc_q[q][i][j] = (f32x4){0.f, 0.f, 0.f, 0.f};

    bf16x8 Bf[2][8];
    float4 rqv[2];

// B-frag load: buffer bidx <- linear step tt = 4*s+q (addresses runtime-ok)
#define LDB(bidx, tt) {                                                        \
    const int q_ = (tt) & 3, s_ = (tt) >> 2;                                   \
    const int r16 = 32 * half + 8 * q_ + 2 * w;                                \
    _Pragma("unroll")                                                          \
    for (int et_ = 0; et_ < 2; et_++)                                          \
    _Pragma("unroll")                                                          \
      for (int cs_ = 0; cs_ < 2; cs_++) {                                      \
        size_t f_ = ((size_t)((r16 + et_) * 32 + 2 * s_ + cs_)) * 512 + l * 8; \
        Bf[bidx][2 * et_ + cs_]     = *(const bf16x8*)(WfH + f_);              \
        Bf[bidx][4 + 2 * et_ + cs_] = *(const bf16x8*)(WfL + f_);              \
      } }

// RQ stage write into buf `par` from rqv (then rqv is free for reload)
#define WQS(par) {                                                             \
    const int wb_ = FRQB(par);                                                 \
    _Pragma("unroll")                                                          \
    for (int i_ = 0; i_ < 2; i_++) {                                           \
      ushort4 h4_, l4_;                                                        \
      hilo(rqv[i_].x, h4_.x, l4_.x); hilo(rqv[i_].y, h4_.y, l4_.y);            \
      hilo(rqv[i_].z, h4_.z, l4_.z); hilo(rqv[i_].w, h4_.w, l4_.w);            \
      *(ushort4*)(sm + wb_ + (16 * i_ + rrow) * 72 + 4 * rcf) = h4_;           \
      *(ushort4*)(sm + wb_ + 2304 + (16 * i_ + rrow) * 72 + 4 * rcf) = l4_;    \
    } }

// One d-stage: par = ss&1 (passed as literal)
#define STAGE(ss, par) {                                                       \
    WQS(par)                                                                   \
    if ((ss) < 15) {                                                           \
      const int d0n_ = 64 * ((ss) + 1);                                        \
      _Pragma("unroll")                                                        \
      for (int i_ = 0; i_ < 2; i_++)                                           \
        rqv[i_] = *(const float4*)(reprF + baseR +                             \
            (size_t)(q0 + 16 * i_ + rrow) * 1024 + d0n_ + 4 * rcf);            \
    }                                                                          \
    bar_lgkm();                                                                \
    const int rqb_ = FRQB(par);                                                \
    bf16x8 ah_[2][2], al_[2][2];                                               \
    _Pragma("unroll")                                                          \
    for (int cs_ = 0; cs_ < 2; cs_++) {                                        \
      ah_[cs_][0] = *(const bf16x8*)(sm + rqb_ + (lr) * 72 + 32 * cs_ + 8 * lg);\
      ah_[cs_][1] = *(const bf16x8*)(sm + rqb_ + (16 + lr) * 72 + 32 * cs_ + 8 * lg);\
      al_[cs_][0] = *(const bf16x8*)(sm + rqb_ + 2304 + (lr) * 72 + 32 * cs_ + 8 * lg);\
      al_[cs_][1] = *(const bf16x8*)(sm + rqb_ + 2304 + (16 + lr) * 72 + 32 * cs_ + 8 * lg);\
    }                                                                          \
    _Pragma("unroll")                                                          \
    for (int q_i = 0; q_i < 4; q_i++) {                                        \
      if (4 * (ss) + q_i < 63) { LDB((q_i + 1) & 1, 4 * (ss) + q_i + 1) }      \
      _Pragma("unroll")                                                        \
      for (int cs_ = 0; cs_ < 2; cs_++)                                        \
      _Pragma("unroll")                                                        \
        for (int et_ = 0; et_ < 2; et_++) {                                    \
          bf16x8 bh_ = Bf[q_i & 1][2 * et_ + cs_];                             \
          bf16x8 bl_ = Bf[q_i & 1][4 + 2 * et_ + cs_];                         \
          acc_q[q_i][0][et_] = MF(ah_[cs_][0], bh_, acc_q[q_i][0][et_]);       \
          acc_q[q_i][0][et_] = MF(ah_[cs_][0], bl_, acc_q[q_i][0][et_]);       \
          acc_q[q_i][0][et_] = MF(al_[cs_][0], bh_, acc_q[q_i][0][et_]);       \
          acc_q[q_i][1][et_] = MF(ah_[cs_][1], bh_, acc_q[q_i][1][et_]);       \
          acc_q[q_i][1][et_] = MF(ah_[cs_][1], bl_, acc_q[q_i][1][et_]);       \
          acc_q[q_i][1][et_] = MF(al_[cs_][1], bh_, acc_q[q_i][1][et_]);       \
        }                                                                      \
    } }

    // prologue: rq(0) + B(t=0) in flight
#pragma unroll
    for (int i = 0; i < 2; i++)
      rqv[i] = *(const float4*)(reprF + baseR + (size_t)(q0 + 16 * i + rrow) * 1024 + 4 * rcf);
    LDB(0, 0)

    for (int sb = 0; sb < 16; sb += 2) {
      STAGE(sb, 0)
      STAGE(sb + 1, 1)
    }
#undef STAGE
#undef WQS
#undef LDB

    // ---------------- A3: S += Q(half) @ K^T, per 128-e chunk --------------
#pragma unroll
    for (int c = 0; c < 4; c++) {
      const int ebase = 512 * half + 128 * c;
      __syncthreads();   // QS region free (prev chunk frag reads / d-sweep done)

      float4 kc0, kc1, kn0, kn1, km0, km1;
#define KLOAD(d0_, d1_, uu) {                                                  \
      const int j_ = (uu) % 5, es_ = (uu) / 5;                                 \
      int kk_ = q0 - 64 + 16 * (ktb + j_) + lr;                                \
      kk_ = kk_ < 0 ? 0 : (kk_ > 2047 ? 2047 : kk_);                           \
      const float* p_ = reprF + baseR + (size_t)kk_ * 1024 + ebase + 32 * es_ + 8 * lg; \
      d0_ = *(const float4*)p_;                                                \
      d1_ = *(const float4*)(p_ + 4);                                          \
    }
      KLOAD(kc0, kc1, 0)
      KLOAD(kn0, kn1, 1)
      KLOAD(km0, km1, 2)

      // QS write from acc_q[c] (hi/lo bf16 split)
#pragma unroll
      for (int qq = 0; qq < 2; qq++)
#pragma unroll
        for (int et = 0; et < 2; et++)
#pragma unroll
          for (int r = 0; r < 4; r++) {
            int row = 16 * qq + 4 * lg + r;
            int col = 32 * w + 16 * et + lr;
            unsigned short hi, lo_;
            hilo(acc_q[c][qq][et][r], hi, lo_);
            sm[FQSH_O + row * 136 + col] = hi;
            sm[FQSL_O + row * 136 + col] = lo_;
          }
      __syncthreads();   // QS visible

      for (int es = 0; es < 4; es++) {
        bf16x8 qh = *(const bf16x8*)(sm + FQSH_O + (16 * qt + lr) * 136 + 32 * es + 8 * lg);
        bf16x8 ql = *(const bf16x8*)(sm + FQSL_O + (16 * qt + lr) * 136 + 32 * es + 8 * lg);
#pragma unroll
        for (int j = 0; j < 5; j++) {
          const int u = 5 * es + j;
          bf16x8 kh, kl;
          cvt8(kc0, kc1, kh, kl);
          kc0 = kn0; kc1 = kn1; kn0 = km0; kn1 = km1;
          if (u < 17) { KLOAD(km0, km1, u + 3) }
          acc_s[j] = MF(qh, kh, acc_s[j]);
          acc_s[j] = MF(qh, kl, acc_s[j]);
          acc_s[j] = MF(ql, kh, acc_s[j]);
        }
      }
#undef KLOAD
    }
  }

  __syncthreads();
  // scores -> Sls (f32, pitch 172) @0 (RQ/QS dead)
#pragma unroll
  for (int j = 0; j < 5; j++)
#pragma unroll
    for (int r = 0; r < 4; r++) {
      int row = 16 * qt + 4 * lg + r;
      int col = 16 * (ktb + j) + lr;
      smf[row * 172 + col] = acc_s[j][r];
    }
  __syncthreads();

  // masked softmax (8 lanes/row), probs -> PBF bf16 (@12288)
  {
    const int row = tid >> 3, l8 = tid & 7;
    int clo = row;          { int t2 = 64 - q0;            if (t2 > clo) clo = t2; }
    int chi = row + 128;    { int t2 = 2047 + 64 - q0;     if (t2 < chi) chi = t2; }
    float m = -1e30f;
    for (int c = l8; c < 160; c += 8)
      if (c >= clo && c <= chi) m = fmaxf(m, smf[row * 172 + c]);
    m = fmaxf(m, __shfl_xor(m, 1));
    m = fmaxf(m, __shfl_xor(m, 2));
    m = fmaxf(m, __shfl_xor(m, 4));
    float ssum = 0.f;
    for (int c = l8; c < 160; c += 8) {
      float e = (c >= clo && c <= chi) ? __expf(smf[row * 172 + c] - m) : 0.f;
      smf[row * 172 + c] = e;
      ssum += e;
    }
    ssum += __shfl_xor(ssum, 1);
    ssum += __shfl_xor(ssum, 2);
    ssum += __shfl_xor(ssum, 4);
    float rinv = 1.f / ssum;
    for (int c = l8; c < 160; c += 8)
      sm[FPBF_O + row * 168 + c] = f2bf(smf[row * 172 + c] * rinv);
  }
  __syncthreads();

  // ---------------- Phase B: ra = P @ V (single-bf16), out = repr+relu -----
  const int dtl = (w & 1) * 2;
  bf16x8 pa[5];
#pragma unroll
  for (int ks = 0; ks < 5; ks++)
    pa[ks] = *(const bf16x8*)(sm + FPBF_O + (16 * qt + lr) * 168 + 32 * ks + 8 * lg);

  float4 vr4[10];
#pragma unroll
  for (int i = 0; i < 10; i++) {
    int slot = i * 256 + tid;
    int k = slot >> 4, g = slot & 15;
    int kk = q0 - 64 + k;
    kk = kk < 0 ? 0 : (kk > 2047 ? 2047 : kk);
    vr4[i] = *(const float4*)(reprF + baseR + (size_t)kk * 1024 + 4 * g);
  }

  for (int dc = 0; dc < 16; dc++) {
    const int d0 = dc * 64;
    __syncthreads();   // previous chunk's VT reads done (dc=0: Sls dead)
#pragma unroll
    for (int i = 0; i < 10; i++) {
      int slot = i * 256 + tid;
      int k = slot >> 4, g = slot & 15;
      sm[vtidx(4 * g + 0, k)] = f2bf(vr4[i].x);
      sm[vtidx(4 * g + 1, k)] = f2bf(vr4[i].y);
      sm[vtidx(4 * g + 2, k)] = f2bf(vr4[i].z);
      sm[vtidx(4 * g + 3, k)] = f2bf(vr4[i].w);
    }
    __syncthreads();
    if (dc < 15) {
      const int d0n = d0 + 64;
#pragma unroll
      for (int i = 0; i < 10; i++) {
        int slot = i * 256 + tid;
        int k = slot >> 4, g = slot & 15;
        int kk = q0 - 64 + k;
        kk = kk < 0 ? 0 : (kk > 2047 ? 2047 : kk);
        vr4[i] = *(const float4*)(reprF + baseR + (size_t)kk * 1024 + d0n + 4 * g);
      }
    }
    f32x4 ra0 = (f32x4){0.f, 0.f, 0.f, 0.f};
    f32x4 ra1 = (f32x4){0.f, 0.f, 0.f, 0.f};
    const int row0 = 16 * dtl + lr, row1 = 16 * (dtl + 1) + lr;
#pragma unroll
    for (int ks = 0; ks < 5; ks++) {
      bf16x8 v0 = *(const bf16x8*)(sm + vtidx(row0, 32 * ks + 8 * lg));
      bf16x8 v1 = *(const bf16x8*)(sm + vtidx(row1, 32 * ks + 8 * lg));
      ra0 = MF(pa[ks], v0, ra0);
      ra1 = MF(pa[ks], v1, ra1);
    }
#pragma unroll
    for (int r = 0; r < 4; r++) {
      int qg = q0 + 16 * qt + 4 * lg + r;
      size_t base = baseR + (size_t)qg * 1024 + d0;
      int dg0 = 16 * dtl + lr, dg1 = 16 * (dtl + 1) + lr;
      outF[base + dg0] = reprF[base + dg0] + fmaxf(ra0[r], 0.f);
      outF[base + dg1] = reprF[base + dg1] + fmaxf(ra1[r], 0.f);
    }
  }
}

extern "C" void kernel_launch(void* const* d_in, const int* in_sizes, int n_in,
                              void* d_out, int out_size, void* d_ws, size_t ws_size,
                              hipStream_t stream) {
  const void* repr = d_in[0];
  const void* W    = d_in[1];
  dim3 grid(SEQL / QT, NB);   // (64, 8) = 512 blocks

  const bool use_mfma = (d_ws != nullptr) && (ws_size >= (size_t)4 * 1024 * 1024);
  if (use_mfma) {
    tposeW2<<<dim3(256), dim3(256), 0, stream>>>(repr, W, d_ws);
    attn_mfma<<<grid, dim3(256), 0, stream>>>(
        (const unsigned short*)repr, (const unsigned short*)d_ws, (unsigned short*)d_out);
    attn_mfma_f32<<<grid, dim3(256), 0, stream>>>(
        (const float*)repr, (const unsigned short*)d_ws,
        (const unsigned short*)d_ws + (1u << 20), (float*)d_out);
  } else {
    attn_fused<true><<<grid, dim3(256), 0, stream>>>(repr, W, d_out);
    attn_fused<false><<<grid, dim3(256), 0, stream>>>(repr, W, d_out);
  }
}